// Round 21
// baseline (139.781 us; speedup 1.0000x reference)
//
#include <hip/hip_runtime.h>
#include <float.h>

#define HEADS 8
#define DIM 64
#define BATCH 2
#define SEQ 2048
#define KNN 32
#define QT 16
#define KT 64
#define NEGF (-3.402823466e38f)

typedef float f32x4 __attribute__((ext_vector_type(4)));
typedef __bf16 bf16x8 __attribute__((ext_vector_type(8)));

union F4 { float4 v; f32x4 e; float f[4]; };
union S8 { bf16x8 b; unsigned int u[4]; unsigned short us[8]; uint4 u4; uint2 u2[2]; };

__device__ __forceinline__ unsigned short f2bf(float x) {
    unsigned int u = __float_as_uint(x);
    u = (u + 0x7fffu + ((u >> 16) & 1u)) >> 16;
    return (unsigned short)u;
}

// ws layout (bytes):
//   flag @0
//   knBt @1024          bf16 tiled K: [b][s16(128)][kc(2)] 1KB frags (512 KB)
//   vTt  @1024+512K     bf16 tiled V: [b][s64(32)][kk2*4+mtd(8)] 1KB frags (512 KB)
//   qnB  @1024+1M       bf16 (B,H,S,D) 4 MB
//   maccG @1024+5M      f32 (B,H,S,D) 8 MB
//   mG @1024+13M, lG @1024+13M+256K   f32 (B,H,S)

__global__ __launch_bounds__(256) void prep_kernel(const float* __restrict__ k,
                                                   const float* __restrict__ v,
                                                   const unsigned char* __restrict__ mmraw,
                                                   unsigned short* __restrict__ knBt,
                                                   unsigned short* __restrict__ vTt,
                                                   int* __restrict__ flag) {
    __shared__ float kn_s[64][65];
    __shared__ float vt_s[64][65];
    const int w = threadIdx.x >> 6, lane = threadIdx.x & 63;
    const int s0 = blockIdx.x * 64;
    const int b = s0 >> 11;
    const int s64 = (s0 & 2047) >> 6;
    for (int rr = 0; rr < 16; rr++) {
        const int sl = w * 16 + rr;
        const int row = s0 + sl;
        float kv = k[(size_t)row * DIM + lane];
        float ssq = kv * kv;
        #pragma unroll
        for (int m = 1; m < 64; m <<= 1) ssq += __shfl_xor(ssq, m);
        kn_s[sl][lane] = kv / fmaxf(sqrtf(ssq), 1e-12f);
        vt_s[sl][lane] = v[(size_t)row * DIM + lane];
    }
    __syncthreads();
    #pragma unroll
    for (int i = 0; i < 2; i++) {
        const int ch = threadIdx.x * 2 + i;
        const int s16g = ch >> 7;
        const int rem = ch & 127;
        const int rowc = rem >> 3;
        const int kc = (rem >> 2) & 1;
        const int oct = rem & 3;
        const float* src = &kn_s[s16g * 16 + rowc][kc * 32 + oct * 8];
        unsigned short tmp[8];
        #pragma unroll
        for (int e = 0; e < 8; e++) tmp[e] = f2bf(src[e]);
        const int s16 = s64 * 4 + s16g;
        unsigned short* dst = knBt + (((size_t)(b * 128 + s16) * 2 + kc) << 9)
                            + rowc * 32 + oct * 8;
        *(uint4*)dst = *(uint4*)&tmp[0];
    }
    #pragma unroll
    for (int i = 0; i < 2; i++) {
        const int ch = threadIdx.x * 2 + i;
        const int kk2 = ch >> 8;
        const int mtd = (ch >> 6) & 3;
        const int cc = (ch >> 2) & 15;
        const int q = ch & 3;
        unsigned short tmp[8];
        #pragma unroll
        for (int e = 0; e < 8; e++)
            tmp[e] = f2bf(vt_s[kk2 * 32 + q * 8 + e][mtd * 16 + cc]);
        unsigned short* dst = vTt + (((size_t)(b * 32 + s64) * 8 + kk2 * 4 + mtd) << 9)
                            + cc * 32 + q * 8;
        *(uint4*)dst = *(uint4*)&tmp[0];
    }
    if (blockIdx.x == 0 && w == 0) {
        int bad = 0;
        #pragma unroll
        for (int t = 0; t < 8; t++) {
            int idx = t * 64 + lane;
            if ((idx & 3) != 0 && mmraw[idx] != 0) bad = 1;
        }
        unsigned long long anybad = __ballot(bad);
        if (lane == 0) flag[0] = (anybad == 0ULL) ? 1 : 0;
    }
}

// Mem-branch streamer (R10, measured ~26us hot): lane-owns-j, minimal cross-lane.
__global__ __launch_bounds__(256, 4) void mem_kernel(
    const float* __restrict__ q,
    const float* __restrict__ scale_param,
    const float* __restrict__ mem_kv,
    const void*  __restrict__ mem_mask,
    const int*   __restrict__ flagp,
    unsigned short* __restrict__ qnB,
    float* __restrict__ maccG,
    float* __restrict__ mG,
    float* __restrict__ lG)
{
    __shared__ float qn_s[4][64];
    __shared__ float p_s[4][32];
    const int w = threadIdx.x >> 6, lane = threadIdx.x & 63;
    const int mask_is_int = flagp[0];
    const int gid = blockIdx.x * 4 + w;
    const float scale = __expf(scale_param[(gid >> 11) & 7]);
    const float* rowp = mem_kv + (size_t)gid * (KNN * 2 * DIM);

    const int j1 = lane & 31, dh = lane >> 5;
    bool mybit;
    {
        size_t mmrow = (size_t)gid * KNN;
        mybit = mask_is_int ? (((const int*)mem_mask)[mmrow + j1] != 0)
                            : (((const unsigned char*)mem_mask)[mmrow + j1] != 0);
    }
    const unsigned int mb = (unsigned int)__ballot(mybit);

    float qv = q[(size_t)gid * DIM + lane];

    F4 dk[8];
    #pragma unroll
    for (int i = 0; i < 8; i++) dk[i].e = 0.f;
    {
        const float* kbase = rowp + j1 * (2 * DIM) + dh * 32;
        if (mybit) {
            #pragma unroll
            for (int i = 0; i < 8; i++) dk[i].e = *(const f32x4*)(kbase + 4 * i);
        }
    }
    const int g = lane >> 4, c16 = lane & 15;
    F4 dv[8];
    #pragma unroll
    for (int t = 0; t < 8; t++) {
        dv[t].e = 0.f;
        const int j2 = 4 * t + g;
        if ((mb >> j2) & 1u)
            dv[t].e = *(const f32x4*)(rowp + j2 * (2 * DIM) + DIM + c16 * 4);
    }

    float ssq = qv * qv;
    #pragma unroll
    for (int m2 = 1; m2 < 64; m2 <<= 1) ssq += __shfl_xor(ssq, m2);
    float qn = qv / fmaxf(sqrtf(ssq), 1e-12f);
    qnB[(size_t)gid * DIM + lane] = f2bf(qn);
    qn_s[w][lane] = qn;

    float s = 0.f;
    #pragma unroll
    for (int i = 0; i < 8; i++) {
        F4 qq; qq.v = *(const float4*)&qn_s[w][dh * 32 + 4 * i];
        s += dk[i].f[0] * qq.f[0] + dk[i].f[1] * qq.f[1]
           + dk[i].f[2] * qq.f[2] + dk[i].f[3] * qq.f[3];
    }
    s += __shfl_xor(s, 32);
    s = mybit ? s * scale : NEGF;

    float mx = s;
    #pragma unroll
    for (int m2 = 1; m2 < 32; m2 <<= 1) mx = fmaxf(mx, __shfl_xor(mx, m2));
    float p = __expf(s - mx);
    float ls = p;
    #pragma unroll
    for (int m2 = 1; m2 < 32; m2 <<= 1) ls += __shfl_xor(ls, m2);
    if (lane < 32) p_s[w][lane] = p;

    f32x4 acc = 0.f;
    #pragma unroll
    for (int t = 0; t < 8; t++) {
        float pv = p_s[w][4 * t + g];
        #pragma unroll
        for (int e = 0; e < 4; e++) acc[e] += pv * dv[t].f[e];
    }
    #pragma unroll
    for (int e = 0; e < 4; e++) {
        acc[e] += __shfl_xor(acc[e], 16);
        acc[e] += __shfl_xor(acc[e], 32);
    }
    if (g == 0) {
        F4 o; o.e = acc;
        *(float4*)(maccG + (size_t)gid * DIM + c16 * 4) = o.v;
    }
    if (lane == 0) { mG[gid] = mx; lG[gid] = ls; }
}

// Flash v8: QT=16 paired blocks (pr, 127-pr) -> 1024 blocks, low VGPR (mt dim
// deleted). Pair work constant (~33 k-tiles); waves split k-tiles stride 4;
// in-kernel merge with mem branch (no partial round-trips).
__global__ __launch_bounds__(256) void flash_kernel(
    const float* __restrict__ scale_param,
    const float* __restrict__ mask,
    const unsigned short* __restrict__ knBt,
    const unsigned short* __restrict__ vTt,
    const unsigned short* __restrict__ qnB,
    const float* __restrict__ maccG,
    const float* __restrict__ mG,
    const float* __restrict__ lG,
    float* __restrict__ out)
{
    __shared__ float maccs[QT][DIM + 4];
    __shared__ float mmem_s[QT], lmem_s[QT];
    __shared__ __attribute__((aligned(16))) unsigned short fragbuf[4][2][4][17][8];
    __shared__ float corr_s[QT];
    __shared__ float mlw[4][2][QT];
    __shared__ float linv_s[QT];

    const int tid = threadIdx.x;
    const int w = tid >> 6;
    const int lane = tid & 63;
    const int g = lane >> 4;
    const int c = lane & 15;
    const int bid = blockIdx.x;
    const int pr = bid & 63;              // pair index 0..63
    const int bh = bid >> 6;
    const int b = bh >> 3;
    const int h = bh & 7;
    const float scale = __expf(scale_param[h]);

    const unsigned short* knTb = knBt + ((size_t)b * 128 * 2 << 9);
    const unsigned short* vTtb = vTt  + ((size_t)b * 32 * 8 << 9);
    const int lofs = c * 32;

    #pragma unroll 1
    for (int half = 0; half < 2; half++) {
        const int qt = half ? (127 - pr) : pr;   // q-tile of 16 rows, 0..127
        const int i0 = qt * QT;

        bf16x8 qa[2];
        #pragma unroll
        for (int kc = 0; kc < 2; kc++) {
            S8 t;
            t.u4 = *(const uint4*)(qnB + ((size_t)bh * SEQ + i0 + c) * DIM + kc * 32 + g * 8);
            qa[kc] = t.b;
        }

        f32x4 oacc[4];
        #pragma unroll
        for (int mtd = 0; mtd < 4; mtd++)
            #pragma unroll
            for (int r = 0; r < 4; r++) oacc[mtd][r] = 0.f;
        float mrow = NEGF, lrow = 0.f;

        const int nkt = ((i0 + QT - 1) >> 6) + 1;

        for (int jt = w; jt < nkt; jt += 4) {
            const int jb = jt * KT;

            bf16x8 va[4][2];
            #pragma unroll
            for (int mtd = 0; mtd < 4; mtd++)
                #pragma unroll
                for (int kk2 = 0; kk2 < 2; kk2++) {
                    const unsigned short* vbase = vTtb + (((size_t)jt * 8 + kk2 * 4 + mtd) << 9) + lofs;
                    S8 t;
                    t.u2[0] = *(const uint2*)(vbase + 4 * g);
                    t.u2[1] = *(const uint2*)(vbase + 16 + 4 * g);
                    va[mtd][kk2] = t.b;
                }

            // QK^T swapped: lane holds S[i = i0+c][j = jb+nt*16+4g+r]
            f32x4 sacc[4];
            #pragma unroll
            for (int nt = 0; nt < 4; nt++)
                #pragma unroll
                for (int r = 0; r < 4; r++) sacc[nt][r] = 0.f;
            #pragma unroll
            for (int kc = 0; kc < 2; kc++) {
                #pragma unroll
                for (int nt = 0; nt < 4; nt++) {
                    S8 kb;
                    kb.u4 = *(const uint4*)(knTb + (((size_t)(jt * 4 + nt) * 2 + kc) << 9) + lofs + g * 8);
                    sacc[nt] = __builtin_amdgcn_mfma_f32_16x16x32_bf16(kb.b, qa[kc], sacc[nt], 0, 0, 0);
                }
            }

            F4 mskv[4];
            #pragma unroll
            for (int nt = 0; nt < 4; nt++)
                mskv[nt].v = *(const float4*)(mask + b * SEQ + jb + nt * 16 + 4 * g);
            const bool docausal = (jb + 63 > i0);

            const int iq = i0 + c;
            float tm = NEGF;
            #pragma unroll
            for (int nt = 0; nt < 4; nt++)
                #pragma unroll
                for (int r = 0; r < 4; r++) {
                    float s = sacc[nt][r] * scale + NEGF * (1.f - mskv[nt].f[r]);
                    if (docausal) {
                        int j = jb + nt * 16 + 4 * g + r;
                        if (j > iq) s = NEGF;
                    }
                    sacc[nt][r] = s;
                    tm = fmaxf(tm, s);
                }
            tm = fmaxf(tm, __shfl_xor(tm, 16));
            tm = fmaxf(tm, __shfl_xor(tm, 32));
            float mnew = fmaxf(mrow, tm);
            float corr = __expf(mrow - mnew);
            mrow = mnew;

            float ps = 0.f;
            #pragma unroll
            for (int nt = 0; nt < 4; nt++) {
                float p0 = __expf(sacc[nt][0] - mnew);
                float p1 = __expf(sacc[nt][1] - mnew);
                float p2 = __expf(sacc[nt][2] - mnew);
                float p3 = __expf(sacc[nt][3] - mnew);
                ps += (p0 + p1) + (p2 + p3);
                unsigned int lo = (unsigned int)f2bf(p0) | ((unsigned int)f2bf(p1) << 16);
                unsigned int hi = (unsigned int)f2bf(p2) | ((unsigned int)f2bf(p3) << 16);
                *(uint2*)&fragbuf[w][nt >> 1][g][c][4 * (nt & 1)] = make_uint2(lo, hi);
            }
            ps += __shfl_xor(ps, 16);
            ps += __shfl_xor(ps, 32);
            lrow = lrow * corr + ps;

            #pragma unroll
            for (int mtd = 0; mtd < 4; mtd++)
                #pragma unroll
                for (int r = 0; r < 4; r++) oacc[mtd][r] *= corr;

            #pragma unroll
            for (int kk2 = 0; kk2 < 2; kk2++) {
                S8 pb; pb.u4 = *(const uint4*)&fragbuf[w][kk2][g][c][0];
                #pragma unroll
                for (int mtd = 0; mtd < 4; mtd++)
                    oacc[mtd] = __builtin_amdgcn_mfma_f32_16x16x32_bf16(va[mtd][kk2], pb.b, oacc[mtd], 0, 0, 0);
            }
        }

        // ---- merge: mem partials + 4 wave-partials (QT=16 rows) ----
        {
            int i = tid >> 4, d0 = (tid & 15) * 4;
            const float* src = maccG + ((size_t)bh * SEQ + i0 + i) * DIM + d0;
            *(float4*)&maccs[i][d0] = *(const float4*)src;
            if (tid < QT) {
                mmem_s[tid] = mG[(size_t)bh * SEQ + i0 + tid];
                lmem_s[tid] = lG[(size_t)bh * SEQ + i0 + tid];
            }
        }
        if (g == 0) {
            mlw[w][0][c] = mrow;
            mlw[w][1][c] = lrow;
        }
        __syncthreads();
        {
            int i = tid >> 4;
            int d0 = (tid & 15) * 4;
            float mM = mmem_s[i];
            #pragma unroll
            for (int w2 = 0; w2 < 4; w2++) mM = fmaxf(mM, mlw[w2][0][i]);
            float em = __expf(mmem_s[i] - mM);
            float L = lmem_s[i] * em;
            #pragma unroll
            for (int w2 = 0; w2 < 4; w2++) L += mlw[w2][1][i] * __expf(mlw[w2][0][i] - mM);
            #pragma unroll
            for (int e = 0; e < 4; e++) maccs[i][d0 + e] *= em;
            if ((tid & 15) == 0) linv_s[i] = 1.f / L;
            if ((tid & 15) == 1) corr_s[i] = mM;
        }
        __syncthreads();
        float ew = __expf(mlw[w][0][c] - corr_s[c]);
        for (int w2 = 0; w2 < 4; w2++) {
            if (w == w2) {
                #pragma unroll
                for (int mtd = 0; mtd < 4; mtd++)
                    #pragma unroll
                    for (int r = 0; r < 4; r++)
                        maccs[c][mtd * 16 + 4 * g + r] += oacc[mtd][r] * ew;
            }
            __syncthreads();
        }
        {
            int i = tid >> 4;
            int d0 = (tid & 15) * 4;
            float inv = linv_s[i];
            F4 o0;
            o0.v = *(const float4*)&maccs[i][d0];
            #pragma unroll
            for (int e = 0; e < 4; e++) o0.f[e] *= inv;
            *(float4*)(out + ((size_t)bh * SEQ + i0 + i) * DIM + d0) = o0.v;
        }
        __syncthreads();   // LDS reused by next half
    }
}

extern "C" void kernel_launch(void* const* d_in, const int* in_sizes, int n_in,
                              void* d_out, int out_size, void* d_ws, size_t ws_size,
                              hipStream_t stream) {
    const float* q           = (const float*)d_in[0];
    const float* k           = (const float*)d_in[1];
    const float* v           = (const float*)d_in[2];
    const float* scale_param = (const float*)d_in[3];
    const float* mem_kv      = (const float*)d_in[4];
    const float* mask        = (const float*)d_in[5];
    const void*  mem_mask    = d_in[6];
    float* out = (float*)d_out;

    char* base = (char*)d_ws;
    int* flag            = (int*)base;
    unsigned short* knBt = (unsigned short*)(base + 1024);
    unsigned short* vTt  = (unsigned short*)(base + 1024 + (512ull << 10));
    unsigned short* qnB  = (unsigned short*)(base + 1024 + (1ull << 20));
    float* maccG         = (float*)(base + 1024 + (5ull << 20));
    float* mG            = (float*)(base + 1024 + (13ull << 20));
    float* lG            = (float*)(base + 1024 + (13ull << 20) + (256ull << 10));

    prep_kernel<<<dim3(BATCH * SEQ / 64), dim3(256), 0, stream>>>(
        k, v, (const unsigned char*)mem_mask, knBt, vTt, flag);
    mem_kernel<<<dim3(BATCH * HEADS * SEQ / 4), dim3(256), 0, stream>>>(
        q, scale_param, mem_kv, mem_mask, flag, qnB, maccG, mG, lG);
    flash_kernel<<<dim3(BATCH * HEADS * (SEQ / QT) / 2), dim3(256), 0, stream>>>(
        scale_param, mask, knBt, vTt, qnB, maccG, mG, lG, out);
}

// Round 22
// 111.070 us; speedup vs baseline: 1.2585x; 1.2585x over previous
//
#include <hip/hip_runtime.h>
#include <float.h>

#define HEADS 8
#define DIM 64
#define BATCH 2
#define SEQ 2048
#define KNN 32
#define QT 32
#define KT 64
#define NEGF (-3.402823466e38f)

typedef float f32x4 __attribute__((ext_vector_type(4)));
typedef __bf16 bf16x8 __attribute__((ext_vector_type(8)));

union F4 { float4 v; f32x4 e; float f[4]; };
union S8 { bf16x8 b; unsigned int u[4]; unsigned short us[8]; uint4 u4; uint2 u2[2]; };

__device__ __forceinline__ unsigned short f2bf(float x) {
    unsigned int u = __float_as_uint(x);
    u = (u + 0x7fffu + ((u >> 16) & 1u)) >> 16;
    return (unsigned short)u;
}

// ws layout (bytes):
//   flag @0
//   knBt @1024          bf16 tiled K: [b][s16(128)][kc(2)] 1KB frags (512 KB)
//   vTt  @1024+512K     bf16 tiled V: [b][s64(32)][kk2*4+mtd(8)] 1KB frags (512 KB)
//   qnB  @1024+1M       bf16 (B,H,S,D) 4 MB
//   maccG @1024+5M      f32 (B,H,S,D) 8 MB
//   mG @1024+13M, lG @1024+13M+256K   f32 (B,H,S)

__global__ __launch_bounds__(256) void prep_kernel(const float* __restrict__ k,
                                                   const float* __restrict__ v,
                                                   const unsigned char* __restrict__ mmraw,
                                                   unsigned short* __restrict__ knBt,
                                                   unsigned short* __restrict__ vTt,
                                                   int* __restrict__ flag) {
    __shared__ float kn_s[64][65];
    __shared__ float vt_s[64][65];
    const int w = threadIdx.x >> 6, lane = threadIdx.x & 63;
    const int s0 = blockIdx.x * 64;
    const int b = s0 >> 11;
    const int s64 = (s0 & 2047) >> 6;
    for (int rr = 0; rr < 16; rr++) {
        const int sl = w * 16 + rr;
        const int row = s0 + sl;
        float kv = k[(size_t)row * DIM + lane];
        float ssq = kv * kv;
        #pragma unroll
        for (int m = 1; m < 64; m <<= 1) ssq += __shfl_xor(ssq, m);
        kn_s[sl][lane] = kv / fmaxf(sqrtf(ssq), 1e-12f);
        vt_s[sl][lane] = v[(size_t)row * DIM + lane];
    }
    __syncthreads();
    #pragma unroll
    for (int i = 0; i < 2; i++) {
        const int ch = threadIdx.x * 2 + i;
        const int s16g = ch >> 7;
        const int rem = ch & 127;
        const int rowc = rem >> 3;
        const int kc = (rem >> 2) & 1;
        const int oct = rem & 3;
        const float* src = &kn_s[s16g * 16 + rowc][kc * 32 + oct * 8];
        unsigned short tmp[8];
        #pragma unroll
        for (int e = 0; e < 8; e++) tmp[e] = f2bf(src[e]);
        const int s16 = s64 * 4 + s16g;
        unsigned short* dst = knBt + (((size_t)(b * 128 + s16) * 2 + kc) << 9)
                            + rowc * 32 + oct * 8;
        *(uint4*)dst = *(uint4*)&tmp[0];
    }
    #pragma unroll
    for (int i = 0; i < 2; i++) {
        const int ch = threadIdx.x * 2 + i;
        const int kk2 = ch >> 8;
        const int mtd = (ch >> 6) & 3;
        const int cc = (ch >> 2) & 15;
        const int q = ch & 3;
        unsigned short tmp[8];
        #pragma unroll
        for (int e = 0; e < 8; e++)
            tmp[e] = f2bf(vt_s[kk2 * 32 + q * 8 + e][mtd * 16 + cc]);
        unsigned short* dst = vTt + (((size_t)(b * 32 + s64) * 8 + kk2 * 4 + mtd) << 9)
                            + cc * 32 + q * 8;
        *(uint4*)dst = *(uint4*)&tmp[0];
    }
    if (blockIdx.x == 0 && w == 0) {
        int bad = 0;
        #pragma unroll
        for (int t = 0; t < 8; t++) {
            int idx = t * 64 + lane;
            if ((idx & 3) != 0 && mmraw[idx] != 0) bad = 1;
        }
        unsigned long long anybad = __ballot(bad);
        if (lane == 0) flag[0] = (anybad == 0ULL) ? 1 : 0;
    }
}

// Mem-branch streamer (R10, measured ~26us hot): lane-owns-j, minimal cross-lane.
__global__ __launch_bounds__(256, 4) void mem_kernel(
    const float* __restrict__ q,
    const float* __restrict__ scale_param,
    const float* __restrict__ mem_kv,
    const void*  __restrict__ mem_mask,
    const int*   __restrict__ flagp,
    unsigned short* __restrict__ qnB,
    float* __restrict__ maccG,
    float* __restrict__ mG,
    float* __restrict__ lG)
{
    __shared__ float qn_s[4][64];
    __shared__ float p_s[4][32];
    const int w = threadIdx.x >> 6, lane = threadIdx.x & 63;
    const int mask_is_int = flagp[0];
    const int gid = blockIdx.x * 4 + w;
    const float scale = __expf(scale_param[(gid >> 11) & 7]);
    const float* rowp = mem_kv + (size_t)gid * (KNN * 2 * DIM);

    const int j1 = lane & 31, dh = lane >> 5;
    bool mybit;
    {
        size_t mmrow = (size_t)gid * KNN;
        mybit = mask_is_int ? (((const int*)mem_mask)[mmrow + j1] != 0)
                            : (((const unsigned char*)mem_mask)[mmrow + j1] != 0);
    }
    const unsigned int mb = (unsigned int)__ballot(mybit);

    float qv = q[(size_t)gid * DIM + lane];

    F4 dk[8];
    #pragma unroll
    for (int i = 0; i < 8; i++) dk[i].e = 0.f;
    {
        const float* kbase = rowp + j1 * (2 * DIM) + dh * 32;
        if (mybit) {
            #pragma unroll
            for (int i = 0; i < 8; i++) dk[i].e = *(const f32x4*)(kbase + 4 * i);
        }
    }
    const int g = lane >> 4, c16 = lane & 15;
    F4 dv[8];
    #pragma unroll
    for (int t = 0; t < 8; t++) {
        dv[t].e = 0.f;
        const int j2 = 4 * t + g;
        if ((mb >> j2) & 1u)
            dv[t].e = *(const f32x4*)(rowp + j2 * (2 * DIM) + DIM + c16 * 4);
    }

    float ssq = qv * qv;
    #pragma unroll
    for (int m2 = 1; m2 < 64; m2 <<= 1) ssq += __shfl_xor(ssq, m2);
    float qn = qv / fmaxf(sqrtf(ssq), 1e-12f);
    qnB[(size_t)gid * DIM + lane] = f2bf(qn);
    qn_s[w][lane] = qn;

    float s = 0.f;
    #pragma unroll
    for (int i = 0; i < 8; i++) {
        F4 qq; qq.v = *(const float4*)&qn_s[w][dh * 32 + 4 * i];
        s += dk[i].f[0] * qq.f[0] + dk[i].f[1] * qq.f[1]
           + dk[i].f[2] * qq.f[2] + dk[i].f[3] * qq.f[3];
    }
    s += __shfl_xor(s, 32);
    s = mybit ? s * scale : NEGF;

    float mx = s;
    #pragma unroll
    for (int m2 = 1; m2 < 32; m2 <<= 1) mx = fmaxf(mx, __shfl_xor(mx, m2));
    float p = __expf(s - mx);
    float ls = p;
    #pragma unroll
    for (int m2 = 1; m2 < 32; m2 <<= 1) ls += __shfl_xor(ls, m2);
    if (lane < 32) p_s[w][lane] = p;

    f32x4 acc = 0.f;
    #pragma unroll
    for (int t = 0; t < 8; t++) {
        float pv = p_s[w][4 * t + g];
        #pragma unroll
        for (int e = 0; e < 4; e++) acc[e] += pv * dv[t].f[e];
    }
    #pragma unroll
    for (int e = 0; e < 4; e++) {
        acc[e] += __shfl_xor(acc[e], 16);
        acc[e] += __shfl_xor(acc[e], 32);
    }
    if (g == 0) {
        F4 o; o.e = acc;
        *(float4*)(maccG + (size_t)gid * DIM + c16 * 4) = o.v;
    }
    if (lane == 0) { mG[gid] = mx; lG[gid] = ls; }
}

// Flash v6 (R19, best): R14 body, causal-PAIRED blocks — q-tiles pr and 63-pr per
// block so every block does exactly 65 k-tile iterations. 512 blocks.
__global__ __launch_bounds__(256) void flash_kernel(
    const float* __restrict__ scale_param,
    const float* __restrict__ mask,
    const unsigned short* __restrict__ knBt,
    const unsigned short* __restrict__ vTt,
    const unsigned short* __restrict__ qnB,
    const float* __restrict__ maccG,
    const float* __restrict__ mG,
    const float* __restrict__ lG,
    float* __restrict__ out)
{
    __shared__ float maccs[QT][DIM + 4];
    __shared__ float mmem_s[QT], lmem_s[QT];
    __shared__ __attribute__((aligned(16))) unsigned short fragbuf[4][2][2][4][17][8];
    __shared__ float corr_s[4][QT];
    __shared__ float mlw[4][2][QT];
    __shared__ float linv_s[QT];

    const int tid = threadIdx.x;
    const int w = tid >> 6;
    const int lane = tid & 63;
    const int g = lane >> 4;
    const int c = lane & 15;
    const int bid = blockIdx.x;
    const int pr = bid & 31;
    const int bh = bid >> 5;
    const int b = bh >> 3;
    const int h = bh & 7;
    const float scale = __expf(scale_param[h]);

    const unsigned short* knTb = knBt + ((size_t)b * 128 * 2 << 9);
    const unsigned short* vTtb = vTt  + ((size_t)b * 32 * 8 << 9);
    const int lofs = c * 32;

    #pragma unroll 1
    for (int half = 0; half < 2; half++) {
        const int qt = half ? (63 - pr) : pr;
        const int i0 = qt * QT;

        bf16x8 qa[2][2];
        #pragma unroll
        for (int mt = 0; mt < 2; mt++)
            #pragma unroll
            for (int kc = 0; kc < 2; kc++) {
                S8 t;
                t.u4 = *(const uint4*)(qnB + ((size_t)bh * SEQ + i0 + mt * 16 + c) * DIM + kc * 32 + g * 8);
                qa[mt][kc] = t.b;
            }

        f32x4 oacc[4][2];
        #pragma unroll
        for (int mtd = 0; mtd < 4; mtd++)
            #pragma unroll
            for (int ni = 0; ni < 2; ni++)
                #pragma unroll
                for (int r = 0; r < 4; r++) oacc[mtd][ni][r] = 0.f;
        float mrow[2] = {NEGF, NEGF}, lrow[2] = {0.f, 0.f};

        const int nkt = ((i0 + QT - 1) >> 6) + 1;

        for (int jt = w; jt < nkt; jt += 4) {
            const int jb = jt * KT;

            bf16x8 va[4][2];
            #pragma unroll
            for (int mtd = 0; mtd < 4; mtd++)
                #pragma unroll
                for (int kk2 = 0; kk2 < 2; kk2++) {
                    const unsigned short* vbase = vTtb + (((size_t)jt * 8 + kk2 * 4 + mtd) << 9) + lofs;
                    S8 t;
                    t.u2[0] = *(const uint2*)(vbase + 4 * g);
                    t.u2[1] = *(const uint2*)(vbase + 16 + 4 * g);
                    va[mtd][kk2] = t.b;
                }

            f32x4 sacc[2][4];
            #pragma unroll
            for (int mt = 0; mt < 2; mt++)
                #pragma unroll
                for (int nt = 0; nt < 4; nt++)
                    #pragma unroll
                    for (int r = 0; r < 4; r++) sacc[mt][nt][r] = 0.f;
            #pragma unroll
            for (int kc = 0; kc < 2; kc++) {
                #pragma unroll
                for (int nt = 0; nt < 4; nt++) {
                    S8 kb;
                    kb.u4 = *(const uint4*)(knTb + (((size_t)(jt * 4 + nt) * 2 + kc) << 9) + lofs + g * 8);
                    #pragma unroll
                    for (int mt = 0; mt < 2; mt++)
                        sacc[mt][nt] = __builtin_amdgcn_mfma_f32_16x16x32_bf16(kb.b, qa[mt][kc], sacc[mt][nt], 0, 0, 0);
                }
            }

            F4 mskv[4];
            #pragma unroll
            for (int nt = 0; nt < 4; nt++)
                mskv[nt].v = *(const float4*)(mask + b * SEQ + jb + nt * 16 + 4 * g);
            const bool docausal = (jb + 63 > i0);

            #pragma unroll
            for (int mt = 0; mt < 2; mt++) {
                const int iq = i0 + mt * 16 + c;
                float tm = NEGF;
                #pragma unroll
                for (int nt = 0; nt < 4; nt++)
                    #pragma unroll
                    for (int r = 0; r < 4; r++) {
                        float s = sacc[mt][nt][r] * scale + NEGF * (1.f - mskv[nt].f[r]);
                        if (docausal) {
                            int j = jb + nt * 16 + 4 * g + r;
                            if (j > iq) s = NEGF;
                        }
                        sacc[mt][nt][r] = s;
                        tm = fmaxf(tm, s);
                    }
                tm = fmaxf(tm, __shfl_xor(tm, 16));
                tm = fmaxf(tm, __shfl_xor(tm, 32));
                float mnew = fmaxf(mrow[mt], tm);
                float corr = __expf(mrow[mt] - mnew);
                mrow[mt] = mnew;

                float ps = 0.f;
                #pragma unroll
                for (int nt = 0; nt < 4; nt++) {
                    unsigned int lo, hi;
                    float p0 = __expf(sacc[mt][nt][0] - mnew);
                    float p1 = __expf(sacc[mt][nt][1] - mnew);
                    float p2 = __expf(sacc[mt][nt][2] - mnew);
                    float p3 = __expf(sacc[mt][nt][3] - mnew);
                    ps += (p0 + p1) + (p2 + p3);
                    lo = (unsigned int)f2bf(p0) | ((unsigned int)f2bf(p1) << 16);
                    hi = (unsigned int)f2bf(p2) | ((unsigned int)f2bf(p3) << 16);
                    *(uint2*)&fragbuf[w][mt][nt >> 1][g][c][4 * (nt & 1)] = make_uint2(lo, hi);
                }
                ps += __shfl_xor(ps, 16);
                ps += __shfl_xor(ps, 32);
                lrow[mt] = lrow[mt] * corr + ps;

                #pragma unroll
                for (int mtd = 0; mtd < 4; mtd++)
                    #pragma unroll
                    for (int r = 0; r < 4; r++) oacc[mtd][mt][r] *= corr;
            }

            #pragma unroll
            for (int kk2 = 0; kk2 < 2; kk2++)
                #pragma unroll
                for (int ni = 0; ni < 2; ni++) {
                    S8 pb; pb.u4 = *(const uint4*)&fragbuf[w][ni][kk2][g][c][0];
                    #pragma unroll
                    for (int mtd = 0; mtd < 4; mtd++)
                        oacc[mtd][ni] = __builtin_amdgcn_mfma_f32_16x16x32_bf16(va[mtd][kk2], pb.b, oacc[mtd][ni], 0, 0, 0);
                }
        }

        {
            int i = tid >> 3, d0 = (tid & 7) * 8;
            const float* src = maccG + ((size_t)bh * SEQ + i0 + i) * DIM + d0;
            *(float4*)&maccs[i][d0]     = *(const float4*)src;
            *(float4*)&maccs[i][d0 + 4] = *(const float4*)(src + 4);
            if (tid < QT) {
                mmem_s[tid] = mG[(size_t)bh * SEQ + i0 + tid];
                lmem_s[tid] = lG[(size_t)bh * SEQ + i0 + tid];
            }
        }
        if (g == 0) {
            #pragma unroll
            for (int mt = 0; mt < 2; mt++) {
                mlw[w][0][mt * 16 + c] = mrow[mt];
                mlw[w][1][mt * 16 + c] = lrow[mt];
            }
        }
        __syncthreads();
        {
            int i = tid >> 3;
            int d0 = (tid & 7) * 8;
            float mM = mmem_s[i];
            #pragma unroll
            for (int w2 = 0; w2 < 4; w2++) mM = fmaxf(mM, mlw[w2][0][i]);
            float em = __expf(mmem_s[i] - mM);
            float L = lmem_s[i] * em;
            #pragma unroll
            for (int w2 = 0; w2 < 4; w2++) L += mlw[w2][1][i] * __expf(mlw[w2][0][i] - mM);
            #pragma unroll
            for (int e = 0; e < 8; e++) maccs[i][d0 + e] *= em;
            if ((tid & 7) == 0) linv_s[i] = 1.f / L;
            if ((tid & 7) == 1) corr_s[0][i] = mM;
        }
        __syncthreads();
        float ew0 = __expf(mlw[w][0][c]      - corr_s[0][c]);
        float ew1 = __expf(mlw[w][0][16 + c] - corr_s[0][16 + c]);
        for (int w2 = 0; w2 < 4; w2++) {
            if (w == w2) {
                #pragma unroll
                for (int mtd = 0; mtd < 4; mtd++)
                    #pragma unroll
                    for (int r = 0; r < 4; r++) {
                        maccs[c][mtd * 16 + 4 * g + r]      += oacc[mtd][0][r] * ew0;
                        maccs[16 + c][mtd * 16 + 4 * g + r] += oacc[mtd][1][r] * ew1;
                    }
            }
            __syncthreads();
        }
        {
            int i = tid >> 3;
            int d0 = (tid & 7) * 8;
            float inv = linv_s[i];
            F4 o0, o1;
            o0.v = *(const float4*)&maccs[i][d0];
            o1.v = *(const float4*)&maccs[i][d0 + 4];
            #pragma unroll
            for (int e = 0; e < 4; e++) { o0.f[e] *= inv; o1.f[e] *= inv; }
            float* op = out + ((size_t)bh * SEQ + i0 + i) * DIM + d0;
            *(float4*)op = o0.v;
            *(float4*)(op + 4) = o1.v;
        }
        __syncthreads();   // LDS reused by next half
    }
}

extern "C" void kernel_launch(void* const* d_in, const int* in_sizes, int n_in,
                              void* d_out, int out_size, void* d_ws, size_t ws_size,
                              hipStream_t stream) {
    const float* q           = (const float*)d_in[0];
    const float* k           = (const float*)d_in[1];
    const float* v           = (const float*)d_in[2];
    const float* scale_param = (const float*)d_in[3];
    const float* mem_kv      = (const float*)d_in[4];
    const float* mask        = (const float*)d_in[5];
    const void*  mem_mask    = d_in[6];
    float* out = (float*)d_out;

    char* base = (char*)d_ws;
    int* flag            = (int*)base;
    unsigned short* knBt = (unsigned short*)(base + 1024);
    unsigned short* vTt  = (unsigned short*)(base + 1024 + (512ull << 10));
    unsigned short* qnB  = (unsigned short*)(base + 1024 + (1ull << 20));
    float* maccG         = (float*)(base + 1024 + (5ull << 20));
    float* mG            = (float*)(base + 1024 + (13ull << 20));
    float* lG            = (float*)(base + 1024 + (13ull << 20) + (256ull << 10));

    prep_kernel<<<dim3(BATCH * SEQ / 64), dim3(256), 0, stream>>>(
        k, v, (const unsigned char*)mem_mask, knBt, vTt, flag);
    mem_kernel<<<dim3(BATCH * HEADS * SEQ / 4), dim3(256), 0, stream>>>(
        q, scale_param, mem_kv, mem_mask, flag, qnB, maccG, mG, lG);
    flash_kernel<<<dim3(BATCH * HEADS * (SEQ / QT) / 2), dim3(256), 0, stream>>>(
        scale_param, mask, knBt, vTt, qnB, maccG, mG, lG, out);
}